// Round 4
// baseline (337.967 us; speedup 1.0000x reference)
//
#include <hip/hip_runtime.h>

#define DEVI __device__ __forceinline__

typedef __attribute__((ext_vector_type(4))) float f32x4;
typedef __attribute__((ext_vector_type(8))) short bf16x8;
typedef __attribute__((ext_vector_type(4))) unsigned int u32x4;

typedef __attribute__((address_space(3))) unsigned int lds_u32_t;
typedef __attribute__((address_space(1))) unsigned int glb_u32_t;

// ---------- constants ----------
constexpr int BATCH = 4096;
constexpr int KTOT  = 66048;          // 65536 main + 256 inp1-linear + 256 inp2-linear
// workspace offsets (bytes)
constexpr size_t OFF_WPT  = 0;                      // Wp_t bf16 [256][66048]  = 33,816,576
constexpr size_t OFF_W2BT = 33816576;               // W2^T bf16 [256][256]    = 131,072
constexpr size_t OFF_B1P  = OFF_W2BT + 131072;      // b1 + W1[66048,:] f32    = 1,024
constexpr size_t OFF_HF   = OFF_B1P + 1024;         // h fp32 [4096][256]      = 4,194,304
constexpr size_t OFF_HB   = OFF_HF + 4194304;       // h bf16 [4096][256]      = 2,097,152

// ---------- bf16 helpers (RNE, no NaN handling needed) ----------
DEVI unsigned int f2bf_u(float x) {
  unsigned int u = __float_as_uint(x);
  return (u + 0x7FFFu + ((u >> 16) & 1u)) >> 16;
}
DEVI unsigned int pack2(float a, float b) { return f2bf_u(a) | (f2bf_u(b) << 16); }

// =====================================================================
// K0: repack W1 (f32 [66049][256]) -> Wp_t (bf16 [256 n][66048 k'])
//     k' order: i*256+j (i,j<256) | 65536+i (j==256 col) | 65792+j (i==256 row)
// =====================================================================
__global__ __launch_bounds__(256) void k_repack(const float* __restrict__ W1,
                                                unsigned short* __restrict__ wpt) {
  __shared__ float tile[64][65];
  int kt = blockIdx.x, nt = blockIdx.y, t = threadIdx.x;
  {
    int r = t >> 2, c4 = (t & 3) * 16;
    int kp = kt * 64 + r;
    int src;
    if (kp < 65536)      src = (kp >> 8) * 257 + (kp & 255);
    else if (kp < 65792) src = (kp - 65536) * 257 + 256;
    else                 src = kp;                    // 256*257 + (kp-65792) == kp
    const float* rp = W1 + (size_t)src * 256 + nt * 64 + c4;
#pragma unroll
    for (int q = 0; q < 4; ++q) {
      f32x4 x = *(const f32x4*)(rp + q * 4);
#pragma unroll
      for (int e = 0; e < 4; ++e) tile[r][c4 + q * 4 + e] = x[e];
    }
  }
  __syncthreads();
  {
    int nl = t >> 2, kk = (t & 3) * 16;
    int n = nt * 64 + nl;
    u32x4 lo, hi;
#pragma unroll
    for (int m = 0; m < 4; ++m)
      lo[m] = pack2(tile[kk + 2 * m][nl], tile[kk + 2 * m + 1][nl]);
#pragma unroll
    for (int m = 0; m < 4; ++m)
      hi[m] = pack2(tile[kk + 8 + 2 * m][nl], tile[kk + 9 + 2 * m][nl]);
    unsigned short* dst = wpt + (size_t)n * KTOT + kt * 64 + kk;
    *(u32x4*)dst = lo;
    *(u32x4*)(dst + 8) = hi;
  }
}

// =====================================================================
// K1: zero h_f32; W2 -> W2^T bf16; b1p = b1 + W1[66048,:]
// =====================================================================
__global__ __launch_bounds__(256) void k_misc(const float* __restrict__ W1,
                                              const float* __restrict__ b1,
                                              const float* __restrict__ W2,
                                              float* __restrict__ hf,
                                              unsigned short* __restrict__ w2bt,
                                              float* __restrict__ b1p) {
  int idx = blockIdx.x * 256 + threadIdx.x;     // grid 4096*256 = 1,048,576
  hf[idx] = 0.f;
  if (idx < 65536) {
    int n2 = idx >> 8, n = idx & 255;
    w2bt[idx] = (unsigned short)f2bf_u(W2[n * 256 + n2]);
  }
  if (idx < 256) b1p[idx] = b1[idx] + W1[(size_t)66048 * 256 + idx];
}

// =====================================================================
// K2: main bilinear GEMM. 256 blocks x 512 thr (8 waves, wave tile 128x64).
//     block = (i-chunk c in [0,16), batch-block bblk in [0,16)); XCD-pinned.
//     Per (i, js64): build A[256][64] bf16 in LDS (swizzled), stage W tile
//     via global_load_lds (source-swizzled), 2 barriers, MFMA 16x16x32.
//     atomicAdd fp32 partials into hf.
// =====================================================================
DEVI void mfma_tiles(const char* A_lds, const char* W_lds, f32x4 (&acc)[8][4],
                     int lane, int wr, int wc) {
  int r16 = lane & 15;
  int kq = lane >> 4;
#pragma unroll
  for (int ks = 0; ks < 2; ++ks) {
    int kun = ks * 4 + kq;
    bf16x8 a[8];
#pragma unroll
    for (int rg = 0; rg < 8; ++rg) {
      int row = wr * 128 + rg * 16 + r16;
      a[rg] = *(const bf16x8*)(A_lds + row * 128 + ((kun ^ (row & 7)) << 4));
    }
#pragma unroll
    for (int cg = 0; cg < 4; ++cg) {
      int n = wc * 64 + cg * 16 + r16;
      bf16x8 bfr = *(const bf16x8*)(W_lds + n * 128 + ((kun ^ (n & 7)) << 4));
#pragma unroll
      for (int rg = 0; rg < 8; ++rg)
        acc[rg][cg] = __builtin_amdgcn_mfma_f32_16x16x32_bf16(a[rg], bfr, acc[rg][cg], 0, 0, 0);
    }
  }
}

DEVI void stage_w(const unsigned short* __restrict__ wpt, char* W_lds, int k0,
                  int w, int lane) {
#pragma unroll
  for (int sI = 0; sI < 4; ++sI) {
    int g = w * 256 + sI * 64 + lane;   // 0..2047 : n = g>>3, unit u = g&7
    int n = g >> 3, u = g & 7;
    size_t gb = (size_t)n * (KTOT * 2) + (size_t)((k0 + ((u ^ (n & 7)) << 3)) * 2);
    __builtin_amdgcn_global_load_lds((const glb_u32_t*)((const char*)wpt + gb),
                                     (lds_u32_t*)(W_lds + g * 16), 16, 0, 0);
  }
}

__global__ __launch_bounds__(512) void k_main(const float* __restrict__ inp1,
                                              const float* __restrict__ inp2,
                                              const unsigned short* __restrict__ wpt,
                                              float* __restrict__ hf) {
  __shared__ u32x4 smem[4096];                    // 64 KiB
  char* A_lds = (char*)smem;                      // [256 b][8 units] bf16, 32 KiB
  char* W_lds = (char*)smem + 32768;              // [256 n][8 units] bf16, 32 KiB

  int lin = blockIdx.x;                           // 0..255
  int xcd = lin & 7, slot = lin >> 3;
  int c = xcd + ((slot >> 4) << 3);               // i-chunk 0..15 (pinned to XCD)
  int bblk = slot & 15;
  int b0 = bblk * 256;
  int i0 = c * 16;

  int t = threadIdx.x;
  int lane = t & 63, w = t >> 6;
  int wr = w >> 2, wc = w & 3;                    // 2 x 4 waves, tile 128 x 64

  int row_a = t >> 1;                             // builder row 0..255
  int ub = (t & 1) * 4;                           // builder unit base

  const float* inp1_row = inp1 + (size_t)(b0 + row_a) * 256;
  const float* inp2_row = inp2 + (size_t)(b0 + row_a) * 256;

  f32x4 acc[8][4] = {};

  for (int js = 0; js < 4; ++js) {
    // cache inp2 segment (32 f32) in registers, reused across 16 i's
    float v[32];
    {
      const f32x4* p = (const f32x4*)(inp2_row + js * 64 + ub * 8);
#pragma unroll
      for (int q = 0; q < 8; ++q) {
        f32x4 x = p[q];
#pragma unroll
        for (int e = 0; e < 4; ++e) v[q * 4 + e] = x[e];
      }
    }
    for (int ii = 0; ii < 16; ++ii) {
      int i = i0 + ii;
      float s = inp1_row[i];
      // build A tile (bf16, XOR-swizzled units)
#pragma unroll
      for (int uu = 0; uu < 4; ++uu) {
        int u = ub + uu;
        u32x4 pk;
#pragma unroll
        for (int m = 0; m < 4; ++m)
          pk[m] = pack2(v[uu * 8 + 2 * m] * s, v[uu * 8 + 2 * m + 1] * s);
        *(u32x4*)(A_lds + row_a * 128 + ((u ^ (row_a & 7)) << 4)) = pk;
      }
      stage_w(wpt, W_lds, i * 256 + js * 64, w, lane);
      __syncthreads();
      mfma_tiles(A_lds, W_lds, acc, lane, wr, wc);
      __syncthreads();
    }
  }

  if (c == 15) {  // linear tail: k' in [65536, 66048)
    for (int jt = 0; jt < 8; ++jt) {
#pragma unroll
      for (int uu = 0; uu < 4; ++uu) {
        int u = ub + uu;
        int koff = jt * 64 + u * 8;               // 0..511
        const float* src = (koff < 256) ? (inp1_row + koff) : (inp2_row + (koff - 256));
        f32x4 x0 = *(const f32x4*)src;
        f32x4 x1 = *(const f32x4*)(src + 4);
        u32x4 pk;
        pk[0] = pack2(x0[0], x0[1]);
        pk[1] = pack2(x0[2], x0[3]);
        pk[2] = pack2(x1[0], x1[1]);
        pk[3] = pack2(x1[2], x1[3]);
        *(u32x4*)(A_lds + row_a * 128 + ((u ^ (row_a & 7)) << 4)) = pk;
      }
      stage_w(wpt, W_lds, 65536 + jt * 64, w, lane);
      __syncthreads();
      mfma_tiles(A_lds, W_lds, acc, lane, wr, wc);
      __syncthreads();
    }
  }

  // epilogue: fp32 atomic accumulate (split-K over 16 chunks)
#pragma unroll
  for (int rg = 0; rg < 8; ++rg)
#pragma unroll
    for (int cg = 0; cg < 4; ++cg) {
      int n = wc * 64 + cg * 16 + (lane & 15);
      int brow = b0 + wr * 128 + rg * 16 + (lane >> 4) * 4;
#pragma unroll
      for (int r = 0; r < 4; ++r)
        atomicAdd(hf + (size_t)(brow + r) * 256 + n, acc[rg][cg][r]);
    }
}

// =====================================================================
// K3: h = relu(hf + b1p) -> bf16
// =====================================================================
__global__ __launch_bounds__(256) void k_finalize(const float* __restrict__ hf,
                                                  const float* __restrict__ b1p,
                                                  unsigned short* __restrict__ hb) {
  int idx = blockIdx.x * 256 + threadIdx.x;
  float v = hf[idx] + b1p[idx & 255];
  hb[idx] = (unsigned short)f2bf_u(v > 0.f ? v : 0.f);
}

// =====================================================================
// K4: out = relu(h @ W2 + b2)  (M=4096, N=256, K=256; frags direct from L2)
// =====================================================================
__global__ __launch_bounds__(256) void k_gemm2(const unsigned short* __restrict__ hb,
                                               const unsigned short* __restrict__ w2bt,
                                               const float* __restrict__ b2,
                                               float* __restrict__ out) {
  int b0 = blockIdx.x * 128, n0 = blockIdx.y * 128;
  int t = threadIdx.x, lane = t & 63, w = t >> 6;
  int wr = w >> 1, wc = w & 1;                    // 2 x 2 waves, tile 64 x 64
  int r16 = lane & 15, k8 = (lane >> 4) * 8;
  f32x4 acc[4][4] = {};
  for (int ks = 0; ks < 8; ++ks) {
    int k = ks * 32 + k8;
    bf16x8 a[4], bb[4];
#pragma unroll
    for (int rg = 0; rg < 4; ++rg) {
      int b_ = b0 + wr * 64 + rg * 16 + r16;
      a[rg] = *(const bf16x8*)(hb + (size_t)b_ * 256 + k);
    }
#pragma unroll
    for (int cg = 0; cg < 4; ++cg) {
      int n2 = n0 + wc * 64 + cg * 16 + r16;
      bb[cg] = *(const bf16x8*)(w2bt + (size_t)n2 * 256 + k);
    }
#pragma unroll
    for (int rg = 0; rg < 4; ++rg)
#pragma unroll
      for (int cg = 0; cg < 4; ++cg)
        acc[rg][cg] = __builtin_amdgcn_mfma_f32_16x16x32_bf16(a[rg], bb[cg], acc[rg][cg], 0, 0, 0);
  }
#pragma unroll
  for (int rg = 0; rg < 4; ++rg)
#pragma unroll
    for (int cg = 0; cg < 4; ++cg) {
      int n2 = n0 + wc * 64 + cg * 16 + r16;
      float bias = b2[n2];
      int brow = b0 + wr * 64 + rg * 16 + (lane >> 4) * 4;
#pragma unroll
      for (int r = 0; r < 4; ++r) {
        float val = acc[rg][cg][r] + bias;
        out[(size_t)(brow + r) * 256 + n2] = val > 0.f ? val : 0.f;
      }
    }
}

// =====================================================================
extern "C" void kernel_launch(void* const* d_in, const int* in_sizes, int n_in,
                              void* d_out, int out_size, void* d_ws, size_t ws_size,
                              hipStream_t stream) {
  const float* inp1 = (const float*)d_in[0];
  const float* inp2 = (const float*)d_in[1];
  const float* W1   = (const float*)d_in[2];
  const float* b1   = (const float*)d_in[3];
  const float* W2   = (const float*)d_in[4];
  const float* b2   = (const float*)d_in[5];
  float* out = (float*)d_out;

  char* ws = (char*)d_ws;
  unsigned short* wpt  = (unsigned short*)(ws + OFF_WPT);
  unsigned short* w2bt = (unsigned short*)(ws + OFF_W2BT);
  float* b1p = (float*)(ws + OFF_B1P);
  float* hf  = (float*)(ws + OFF_HF);
  unsigned short* hb = (unsigned short*)(ws + OFF_HB);

  k_repack<<<dim3(1032, 4), 256, 0, stream>>>(W1, wpt);
  k_misc<<<4096, 256, 0, stream>>>(W1, b1, W2, hf, w2bt, b1p);
  k_main<<<256, 512, 0, stream>>>(inp1, inp2, wpt, hf);
  k_finalize<<<4096, 256, 0, stream>>>(hf, b1p, hb);
  k_gemm2<<<dim3(32, 2), 256, 0, stream>>>(hb, w2bt, b2, out);
}

// Round 5
// 310.383 us; speedup vs baseline: 1.0889x; 1.0889x over previous
//
#include <hip/hip_runtime.h>

#define DEVI __device__ __forceinline__

typedef __attribute__((ext_vector_type(4))) float f32x4;
typedef __attribute__((ext_vector_type(8))) short bf16x8;
typedef __attribute__((ext_vector_type(4))) unsigned int u32x4;

typedef __attribute__((address_space(3))) unsigned int lds_u32_t;
typedef __attribute__((address_space(1))) unsigned int glb_u32_t;

// ---------- constants ----------
constexpr int KTOT  = 66048;          // 65536 main + 256 inp1-linear + 256 inp2-linear
// workspace offsets (bytes)
constexpr size_t OFF_WPT  = 0;                      // Wp_t bf16 [256][66048]  = 33,816,576
constexpr size_t OFF_W2BT = 33816576;               // W2^T bf16 [256][256]    = 131,072
constexpr size_t OFF_B1P  = OFF_W2BT + 131072;      // b1 + W1[66048,:] f32    = 1,024
constexpr size_t OFF_HF   = OFF_B1P + 1024;         // h fp32 [4096][256]      = 4,194,304
constexpr size_t OFF_HB   = OFF_HF + 4194304;       // h bf16 [4096][256]      = 2,097,152

// ---------- bf16 helpers (RNE) ----------
DEVI unsigned int f2bf_u(float x) {
  unsigned int u = __float_as_uint(x);
  return (u + 0x7FFFu + ((u >> 16) & 1u)) >> 16;
}
DEVI unsigned int pack2(float a, float b) { return f2bf_u(a) | (f2bf_u(b) << 16); }

// =====================================================================
// K0: repack W1 (f32 [66049][256]) -> Wp_t (bf16 [256 n][66048 k'])
// =====================================================================
__global__ __launch_bounds__(256) void k_repack(const float* __restrict__ W1,
                                                unsigned short* __restrict__ wpt) {
  __shared__ float tile[64][65];
  int kt = blockIdx.x, nt = blockIdx.y, t = threadIdx.x;
  {
    int r = t >> 2, c4 = (t & 3) * 16;
    int kp = kt * 64 + r;
    int src;
    if (kp < 65536)      src = (kp >> 8) * 257 + (kp & 255);
    else if (kp < 65792) src = (kp - 65536) * 257 + 256;
    else                 src = kp;
    const float* rp = W1 + (size_t)src * 256 + nt * 64 + c4;
#pragma unroll
    for (int q = 0; q < 4; ++q) {
      f32x4 x = *(const f32x4*)(rp + q * 4);
#pragma unroll
      for (int e = 0; e < 4; ++e) tile[r][c4 + q * 4 + e] = x[e];
    }
  }
  __syncthreads();
  {
    int nl = t >> 2, kk = (t & 3) * 16;
    int n = nt * 64 + nl;
    u32x4 lo, hi;
#pragma unroll
    for (int m = 0; m < 4; ++m)
      lo[m] = pack2(tile[kk + 2 * m][nl], tile[kk + 2 * m + 1][nl]);
#pragma unroll
    for (int m = 0; m < 4; ++m)
      hi[m] = pack2(tile[kk + 8 + 2 * m][nl], tile[kk + 9 + 2 * m][nl]);
    unsigned short* dst = wpt + (size_t)n * KTOT + kt * 64 + kk;
    *(u32x4*)dst = lo;
    *(u32x4*)(dst + 8) = hi;
  }
}

// =====================================================================
// K1: zero h_f32; W2 -> W2^T bf16; b1p = b1 + W1[66048,:]
// =====================================================================
__global__ __launch_bounds__(256) void k_misc(const float* __restrict__ W1,
                                              const float* __restrict__ b1,
                                              const float* __restrict__ W2,
                                              float* __restrict__ hf,
                                              unsigned short* __restrict__ w2bt,
                                              float* __restrict__ b1p) {
  int idx = blockIdx.x * 256 + threadIdx.x;
  hf[idx] = 0.f;
  if (idx < 65536) {
    int n2 = idx >> 8, n = idx & 255;
    w2bt[idx] = (unsigned short)f2bf_u(W2[n * 256 + n2]);
  }
  if (idx < 256) b1p[idx] = b1[idx] + W1[(size_t)66048 * 256 + idx];
}

// =====================================================================
// K2: main bilinear GEMM — double-buffered 2-phase pipeline.
//     Per step: issue stage_w(next) + build_A(next), then ds_read+MFMA(cur),
//     ONE barrier. Loads overlap the full MFMA phase (T3 minimum-2-phase).
// =====================================================================
DEVI void mfma_tiles(const char* A_lds, const char* W_lds, f32x4 (&acc)[8][4],
                     int lane, int wr, int wc) {
  int r16 = lane & 15;
  int kq = lane >> 4;
#pragma unroll
  for (int ks = 0; ks < 2; ++ks) {
    int kun = ks * 4 + kq;
    bf16x8 a[8];
#pragma unroll
    for (int rg = 0; rg < 8; ++rg) {
      int row = wr * 128 + rg * 16 + r16;
      a[rg] = *(const bf16x8*)(A_lds + row * 128 + ((kun ^ (row & 7)) << 4));
    }
#pragma unroll
    for (int cg = 0; cg < 4; ++cg) {
      int n = wc * 64 + cg * 16 + r16;
      bf16x8 bfr = *(const bf16x8*)(W_lds + n * 128 + ((kun ^ (n & 7)) << 4));
#pragma unroll
      for (int rg = 0; rg < 8; ++rg)
        acc[rg][cg] = __builtin_amdgcn_mfma_f32_16x16x32_bf16(a[rg], bfr, acc[rg][cg], 0, 0, 0);
    }
  }
}

DEVI void stage_w(const unsigned short* __restrict__ wpt, char* W_lds, int k0,
                  int w, int lane) {
#pragma unroll
  for (int sI = 0; sI < 4; ++sI) {
    int g = w * 256 + sI * 64 + lane;   // 0..2047 : n = g>>3, unit u = g&7
    int n = g >> 3, u = g & 7;
    size_t gb = (size_t)n * (KTOT * 2) + (size_t)((k0 + ((u ^ (n & 7)) << 3)) * 2);
    __builtin_amdgcn_global_load_lds((const glb_u32_t*)((const char*)wpt + gb),
                                     (lds_u32_t*)(W_lds + g * 16), 16, 0, 0);
  }
}

__global__ __launch_bounds__(512) void k_main(const float* __restrict__ inp1,
                                              const float* __restrict__ inp2,
                                              const unsigned short* __restrict__ wpt,
                                              float* __restrict__ hf) {
  __shared__ u32x4 smem[8192];                    // 128 KiB: 2 x (A 32K + W 32K)
  char* base = (char*)smem;

  int lin = blockIdx.x;                           // 0..255
  int xcd = lin & 7, slot = lin >> 3;
  int c = xcd + ((slot >> 4) << 3);               // i-chunk 0..15 (pinned to XCD)
  int bblk = slot & 15;
  int b0 = bblk * 256;
  int i0 = c * 16;

  int t = threadIdx.x;
  int lane = t & 63, w = t >> 6;
  int wr = w >> 2, wc = w & 3;                    // 2 x 4 waves, tile 128 x 64

  int row_a = t >> 1;                             // builder row 0..255
  int ub = (t & 1) * 4;                           // builder unit base

  const float* inp1_row = inp1 + (size_t)(b0 + row_a) * 256;
  const float* inp2_row = inp2 + (size_t)(b0 + row_a) * 256;

  // prefetch this chunk's 16 inp1 scalars into registers
  float s1[16];
  {
    const f32x4* p = (const f32x4*)(inp1_row + i0);
#pragma unroll
    for (int q = 0; q < 4; ++q) {
      f32x4 x = p[q];
#pragma unroll
      for (int e = 0; e < 4; ++e) s1[q * 4 + e] = x[e];
    }
  }

  float v[32];
  int js_cur = -1;
  auto loadv = [&](int js) {
    const f32x4* p = (const f32x4*)(inp2_row + js * 64 + ub * 8);
#pragma unroll
    for (int q = 0; q < 8; ++q) {
      f32x4 x = p[q];
#pragma unroll
      for (int e = 0; e < 4; ++e) v[q * 4 + e] = x[e];
    }
    js_cur = js;
  };

  auto build_main = [&](char* A_lds, int ii) {
    float s = s1[ii];
#pragma unroll
    for (int uu = 0; uu < 4; ++uu) {
      int u = ub + uu;
      u32x4 pk;
#pragma unroll
      for (int m = 0; m < 4; ++m)
        pk[m] = pack2(v[uu * 8 + 2 * m] * s, v[uu * 8 + 2 * m + 1] * s);
      *(u32x4*)(A_lds + row_a * 128 + ((u ^ (row_a & 7)) << 4)) = pk;
    }
  };

  auto build_tail = [&](char* A_lds, int jt) {
#pragma unroll
    for (int uu = 0; uu < 4; ++uu) {
      int u = ub + uu;
      int koff = jt * 64 + u * 8;                 // 0..511
      const float* src = (koff < 256) ? (inp1_row + koff) : (inp2_row + (koff - 256));
      f32x4 x0 = *(const f32x4*)src;
      f32x4 x1 = *(const f32x4*)(src + 4);
      u32x4 pk;
      pk[0] = pack2(x0[0], x0[1]);
      pk[1] = pack2(x0[2], x0[3]);
      pk[2] = pack2(x1[0], x1[1]);
      pk[3] = pack2(x1[2], x1[3]);
      *(u32x4*)(A_lds + row_a * 128 + ((u ^ (row_a & 7)) << 4)) = pk;
    }
  };

  f32x4 acc[8][4] = {};

  const int NS = 64 + (c >= 8 ? 1 : 0);           // tail step: k' 65536 + (c-8)*64

  // prologue: stage step 0 into buffer 0
  loadv(0);
  stage_w(wpt, base + 32768, i0 * 256, w, lane);  // W buf0
  build_main(base, 0);                            // A buf0
  __syncthreads();

  for (int s = 0; s < NS; ++s) {
    int cur = s & 1, nxt = cur ^ 1;
    char* A_cur = base + cur * 65536;
    char* W_cur = base + cur * 65536 + 32768;
    char* A_nxt = base + nxt * 65536;
    char* W_nxt = base + nxt * 65536 + 32768;

    int sn = s + 1;
    if (sn < NS) {
      if (sn < 64) {
        int js = sn >> 4, ii = sn & 15;
        stage_w(wpt, W_nxt, (i0 + ii) * 256 + js * 64, w, lane);
        if (js != js_cur) loadv(js);
        build_main(A_nxt, ii);
      } else {
        stage_w(wpt, W_nxt, 65536 + (c - 8) * 64, w, lane);
        build_tail(A_nxt, c - 8);
      }
    }

    mfma_tiles(A_cur, W_cur, acc, lane, wr, wc);
    __syncthreads();
  }

  // epilogue: fp32 atomic accumulate (split-K over 16 chunks)
#pragma unroll
  for (int rg = 0; rg < 8; ++rg)
#pragma unroll
    for (int cg = 0; cg < 4; ++cg) {
      int n = wc * 64 + cg * 16 + (lane & 15);
      int brow = b0 + wr * 128 + rg * 16 + (lane >> 4) * 4;
#pragma unroll
      for (int r = 0; r < 4; ++r)
        atomicAdd(hf + (size_t)(brow + r) * 256 + n, acc[rg][cg][r]);
    }
}

// =====================================================================
// K3: h = relu(hf + b1p) -> bf16
// =====================================================================
__global__ __launch_bounds__(256) void k_finalize(const float* __restrict__ hf,
                                                  const float* __restrict__ b1p,
                                                  unsigned short* __restrict__ hb) {
  int idx = blockIdx.x * 256 + threadIdx.x;
  float v = hf[idx] + b1p[idx & 255];
  hb[idx] = (unsigned short)f2bf_u(v > 0.f ? v : 0.f);
}

// =====================================================================
// K4: out = relu(h @ W2 + b2)
// =====================================================================
__global__ __launch_bounds__(256) void k_gemm2(const unsigned short* __restrict__ hb,
                                               const unsigned short* __restrict__ w2bt,
                                               const float* __restrict__ b2,
                                               float* __restrict__ out) {
  int b0 = blockIdx.x * 128, n0 = blockIdx.y * 128;
  int t = threadIdx.x, lane = t & 63, w = t >> 6;
  int wr = w >> 1, wc = w & 1;
  int r16 = lane & 15, k8 = (lane >> 4) * 8;
  f32x4 acc[4][4] = {};
  for (int ks = 0; ks < 8; ++ks) {
    int k = ks * 32 + k8;
    bf16x8 a[4], bb[4];
#pragma unroll
    for (int rg = 0; rg < 4; ++rg) {
      int b_ = b0 + wr * 64 + rg * 16 + r16;
      a[rg] = *(const bf16x8*)(hb + (size_t)b_ * 256 + k);
    }
#pragma unroll
    for (int cg = 0; cg < 4; ++cg) {
      int n2 = n0 + wc * 64 + cg * 16 + r16;
      bb[cg] = *(const bf16x8*)(w2bt + (size_t)n2 * 256 + k);
    }
#pragma unroll
    for (int rg = 0; rg < 4; ++rg)
#pragma unroll
      for (int cg = 0; cg < 4; ++cg)
        acc[rg][cg] = __builtin_amdgcn_mfma_f32_16x16x32_bf16(a[rg], bb[cg], acc[rg][cg], 0, 0, 0);
  }
#pragma unroll
  for (int rg = 0; rg < 4; ++rg)
#pragma unroll
    for (int cg = 0; cg < 4; ++cg) {
      int n2 = n0 + wc * 64 + cg * 16 + r16;
      float bias = b2[n2];
      int brow = b0 + wr * 64 + rg * 16 + (lane >> 4) * 4;
#pragma unroll
      for (int r = 0; r < 4; ++r) {
        float val = acc[rg][cg][r] + bias;
        out[(size_t)(brow + r) * 256 + n2] = val > 0.f ? val : 0.f;
      }
    }
}

// =====================================================================
extern "C" void kernel_launch(void* const* d_in, const int* in_sizes, int n_in,
                              void* d_out, int out_size, void* d_ws, size_t ws_size,
                              hipStream_t stream) {
  const float* inp1 = (const float*)d_in[0];
  const float* inp2 = (const float*)d_in[1];
  const float* W1   = (const float*)d_in[2];
  const float* b1   = (const float*)d_in[3];
  const float* W2   = (const float*)d_in[4];
  const float* b2   = (const float*)d_in[5];
  float* out = (float*)d_out;

  char* ws = (char*)d_ws;
  unsigned short* wpt  = (unsigned short*)(ws + OFF_WPT);
  unsigned short* w2bt = (unsigned short*)(ws + OFF_W2BT);
  float* b1p = (float*)(ws + OFF_B1P);
  float* hf  = (float*)(ws + OFF_HF);
  unsigned short* hb = (unsigned short*)(ws + OFF_HB);

  k_repack<<<dim3(1032, 4), 256, 0, stream>>>(W1, wpt);
  k_misc<<<4096, 256, 0, stream>>>(W1, b1, W2, hf, w2bt, b1p);
  k_main<<<256, 512, 0, stream>>>(inp1, inp2, wpt, hf);
  k_finalize<<<4096, 256, 0, stream>>>(hf, b1p, hb);
  k_gemm2<<<dim3(32, 2), 256, 0, stream>>>(hb, w2bt, b2, out);
}